// Round 1
// baseline (29.974 us; speedup 1.0000x reference)
//
#include <hip/hip_runtime.h>

#define B_SZ   256
#define N_IN   128
#define F_IN   64
#define G_SZ   128
#define F_OUT  64
#define S_SZ   16
#define K_TOT  1024   // S_SZ * F_IN

#define M_TILE 128
#define BK     64
#define THREADS 512   // 8 waves: wave grid 4 (M) x 2 (N)

// LDS row stride in bf16 elements: 64 + 8 pad = 72 (144 B, keeps 16B alignment,
// breaks the 128B power-of-2 stride -> <=2-way bank aliasing on ds_read_b128)
#define LDSTRIDE 72

typedef __attribute__((ext_vector_type(8))) short short8;  // 8 bf16 (4 VGPRs)
typedef __attribute__((ext_vector_type(4))) float f32x4;

static __device__ __forceinline__ unsigned short f2bf(float f) {
    union { float f; unsigned int u; } v; v.f = f;
    unsigned int r = v.u + 0x7fffu + ((v.u >> 16) & 1u);   // RNE
    return (unsigned short)(r >> 16);
}

__global__ __launch_bounds__(THREADS)
void sparse_linear_kernel(const float* __restrict__ x,
                          const int*   __restrict__ idx,
                          const float* __restrict__ W,
                          const float* __restrict__ bias,
                          float*       __restrict__ out)
{
    __shared__ unsigned short Alds[M_TILE * LDSTRIDE];
    __shared__ unsigned short Wlds[F_OUT * LDSTRIDE];

    const int blk   = blockIdx.x;
    const int g     = blk >> 1;          // 128 groups
    const int mt    = blk & 1;           // 2 m-tiles of 128 batches
    const int bbase = mt * M_TILE;

    const int tid  = threadIdx.x;
    const int wave = tid >> 6;
    const int lane = tid & 63;
    const int wr   = wave >> 1;          // 0..3  (M direction, 32 rows each)
    const int wc   = wave & 1;           // 0..1  (N direction, 32 cols each)

    const int lmod = lane & 15;
    const int ldiv = lane >> 4;

    f32x4 acc[2][2] = {};                // 2 m-frags x 2 n-frags of 16x16

    const float* Wg = W + (size_t)g * F_OUT * K_TOT;

    for (int t = 0; t < K_TOT / BK; ++t) {
        // ---- stage A: gathered x rows -> bf16 LDS tile [128][64] ----
        // K-step t covers k = t*64 .. t*64+63  == s = t, f = 0..63
        const int   row  = idx[g * S_SZ + t];              // wave-uniform -> s_load
        const float* srcA = x + (size_t)bbase * (N_IN * F_IN) + (size_t)row * F_IN;
        #pragma unroll
        for (int i = 0; i < 4; ++i) {
            int id = tid + i * THREADS;                    // 0..2047
            int m  = id >> 4;
            int f  = (id & 15) << 2;
            const float4 v = *reinterpret_cast<const float4*>(srcA + (size_t)m * (N_IN * F_IN) + f);
            uint2 p;
            p.x = ((unsigned int)f2bf(v.y) << 16) | f2bf(v.x);
            p.y = ((unsigned int)f2bf(v.w) << 16) | f2bf(v.z);
            *reinterpret_cast<uint2*>(
                reinterpret_cast<char*>(Alds) + m * (LDSTRIDE * 2) + f * 2) = p;
        }
        // ---- stage W: [64][64] fp32 -> bf16 LDS ----
        const float* srcW = Wg + t * BK;
        #pragma unroll
        for (int i = 0; i < 2; ++i) {
            int id = tid + i * THREADS;                    // 0..1023
            int o  = id >> 4;
            int f  = (id & 15) << 2;
            const float4 v = *reinterpret_cast<const float4*>(srcW + (size_t)o * K_TOT + f);
            uint2 p;
            p.x = ((unsigned int)f2bf(v.y) << 16) | f2bf(v.x);
            p.y = ((unsigned int)f2bf(v.w) << 16) | f2bf(v.z);
            *reinterpret_cast<uint2*>(
                reinterpret_cast<char*>(Wlds) + o * (LDSTRIDE * 2) + f * 2) = p;
        }
        __syncthreads();

        // ---- MFMA: 2 k-subticks of 32, 8 MFMAs per wave ----
        #pragma unroll
        for (int ks = 0; ks < 2; ++ks) {
            const int kb = ks * 32 + (ldiv << 3);          // lane's k base (8 bf16)
            short8 a[2], bfr[2];
            #pragma unroll
            for (int mi = 0; mi < 2; ++mi)
                a[mi] = *reinterpret_cast<const short8*>(
                    reinterpret_cast<const char*>(Alds) +
                    (wr * 32 + mi * 16 + lmod) * (LDSTRIDE * 2) + kb * 2);
            #pragma unroll
            for (int ni = 0; ni < 2; ++ni)
                bfr[ni] = *reinterpret_cast<const short8*>(
                    reinterpret_cast<const char*>(Wlds) +
                    (wc * 32 + ni * 16 + lmod) * (LDSTRIDE * 2) + kb * 2);
            #pragma unroll
            for (int mi = 0; mi < 2; ++mi)
                #pragma unroll
                for (int ni = 0; ni < 2; ++ni)
                    acc[mi][ni] = __builtin_amdgcn_mfma_f32_16x16x32_bf16(
                        a[mi], bfr[ni], acc[mi][ni], 0, 0, 0);
        }
        __syncthreads();
    }

    // ---- epilogue: D[row = 4*(lane>>4)+r][col = lane&15] per fragment ----
    const int rowbase = bbase + wr * 32 + (ldiv << 2);
    #pragma unroll
    for (int ni = 0; ni < 2; ++ni) {
        const int o  = wc * 32 + ni * 16 + lmod;
        const float bv = bias[g * F_OUT + o];
        #pragma unroll
        for (int mi = 0; mi < 2; ++mi) {
            #pragma unroll
            for (int r = 0; r < 4; ++r) {
                const int brow = rowbase + mi * 16 + r;
                out[(size_t)brow * (G_SZ * F_OUT) + g * F_OUT + o] = acc[mi][ni][r] + bv;
            }
        }
    }
}

extern "C" void kernel_launch(void* const* d_in, const int* in_sizes, int n_in,
                              void* d_out, int out_size, void* d_ws, size_t ws_size,
                              hipStream_t stream) {
    const float* x    = (const float*)d_in[0];
    const int*   idx  = (const int*)d_in[1];
    const float* W    = (const float*)d_in[2];
    const float* bias = (const float*)d_in[3];
    float*       out  = (float*)d_out;

    sparse_linear_kernel<<<dim3(G_SZ * (B_SZ / M_TILE)), dim3(THREADS), 0, stream>>>(
        x, idx, W, bias, out);
}

// Round 2
// 26.804 us; speedup vs baseline: 1.1183x; 1.1183x over previous
//
#include <hip/hip_runtime.h>
#include <hip/hip_bf16.h>

#define B_SZ   256
#define N_IN   128
#define F_IN   64
#define G_SZ   128
#define F_OUT  64
#define S_SZ   16
#define K_TOT  1024   // S_SZ * F_IN

#define M_TILE 128
#define BK     64
#define NSTEP  16     // K_TOT / BK
#define THREADS 512   // 8 waves: wave grid 4 (M) x 2 (N)

// LDS row stride in bf16 elements: 64 + 8 pad = 72 (144 B): <=2-way bank
// aliasing on ds_read_b128 (free per m136)
#define LDSTRIDE 72

typedef __attribute__((ext_vector_type(8))) short short8;  // 8 bf16 (4 VGPRs)
typedef __attribute__((ext_vector_type(4))) float f32x4;

static __device__ __forceinline__ unsigned int packbf2(float a, float b) {
    // low 16 bits = a, high 16 bits = b (RNE); compiler emits v_cvt_pk_bf16_f32
    __hip_bfloat162 h = __float22bfloat162_rn(make_float2(a, b));
    union { __hip_bfloat162 h; unsigned int u; } c;
    c.h = h;
    return c.u;
}

__global__ __launch_bounds__(THREADS)
void sparse_linear_kernel(const float* __restrict__ x,
                          const int*   __restrict__ idx,
                          const float* __restrict__ W,
                          const float* __restrict__ bias,
                          float*       __restrict__ out)
{
    __shared__ unsigned short Alds[2][M_TILE * LDSTRIDE];
    __shared__ unsigned short Wlds[2][F_OUT * LDSTRIDE];

    const int blk = blockIdx.x;
    // XCD pairing: blocks b and b+128 share W[g]; 128 % 8 == 0 -> same XCD L2
    const int g     = blk & 127;
    const int mt    = blk >> 7;
    const int bbase = mt * M_TILE;

    const int tid  = threadIdx.x;
    const int wave = tid >> 6;
    const int lane = tid & 63;
    const int wr   = wave >> 1;          // 0..3  (M direction, 32 rows each)
    const int wc   = wave & 1;           // 0..1  (N direction, 32 cols each)
    const int lmod = lane & 15;
    const int ldiv = lane >> 4;

    // ---- fixed per-thread staging addresses ----
    // A: i in 0..3: id = tid + i*512 -> m = id>>4 (0..127), f = (id&15)*4
    const float* aptr[4];
    int am[4], af[4];
    #pragma unroll
    for (int i = 0; i < 4; ++i) {
        int id = tid + i * THREADS;
        am[i] = id >> 4;
        af[i] = (id & 15) << 2;
        aptr[i] = x + (size_t)(bbase + am[i]) * (N_IN * F_IN) + af[i];
    }
    // W: i in 0..1: id -> o = id>>4 (0..63), f = (id&15)*4
    const float* Wg = W + (size_t)g * F_OUT * K_TOT;
    const float* wptr[2];
    int wo[2], wf[2];
    #pragma unroll
    for (int i = 0; i < 2; ++i) {
        int id = tid + i * THREADS;
        wo[i] = id >> 4;
        wf[i] = (id & 15) << 2;
        wptr[i] = Wg + (size_t)wo[i] * K_TOT + wf[i];
    }

    f32x4 acc[2][2] = {};                // 2 m-frags x 2 n-frags of 16x16
    float4 ra[4], rw[2];                 // in-flight prefetch registers

    // issue global loads for K-step t (one gathered x row: s = t, f = 0..63)
    #define LOADT(t)                                                          \
        {                                                                     \
            const int row = idx[g * S_SZ + (t)];                              \
            _Pragma("unroll")                                                 \
            for (int i = 0; i < 4; ++i)                                       \
                ra[i] = *reinterpret_cast<const float4*>(aptr[i] + row * F_IN);\
            _Pragma("unroll")                                                 \
            for (int i = 0; i < 2; ++i)                                       \
                rw[i] = *reinterpret_cast<const float4*>(wptr[i] + (t) * BK); \
        }

    // convert + write staged registers into LDS buffer `buf`
    #define STORET(buf)                                                       \
        {                                                                     \
            _Pragma("unroll")                                                 \
            for (int i = 0; i < 4; ++i) {                                     \
                uint2 p;                                                      \
                p.x = packbf2(ra[i].x, ra[i].y);                              \
                p.y = packbf2(ra[i].z, ra[i].w);                              \
                *reinterpret_cast<uint2*>(                                    \
                    reinterpret_cast<char*>(Alds[buf]) +                      \
                    am[i] * (LDSTRIDE * 2) + af[i] * 2) = p;                  \
            }                                                                 \
            _Pragma("unroll")                                                 \
            for (int i = 0; i < 2; ++i) {                                     \
                uint2 p;                                                      \
                p.x = packbf2(rw[i].x, rw[i].y);                              \
                p.y = packbf2(rw[i].z, rw[i].w);                              \
                *reinterpret_cast<uint2*>(                                    \
                    reinterpret_cast<char*>(Wlds[buf]) +                      \
                    wo[i] * (LDSTRIDE * 2) + wf[i] * 2) = p;                  \
            }                                                                 \
        }

    #define COMPUTE(buf)                                                      \
        {                                                                     \
            _Pragma("unroll")                                                 \
            for (int ks = 0; ks < 2; ++ks) {                                  \
                const int kb = ks * 32 + (ldiv << 3);                         \
                short8 a[2], bfr[2];                                          \
                _Pragma("unroll")                                             \
                for (int mi = 0; mi < 2; ++mi)                                \
                    a[mi] = *reinterpret_cast<const short8*>(                 \
                        reinterpret_cast<const char*>(Alds[buf]) +            \
                        (wr * 32 + mi * 16 + lmod) * (LDSTRIDE * 2) + kb * 2);\
                _Pragma("unroll")                                             \
                for (int ni = 0; ni < 2; ++ni)                                \
                    bfr[ni] = *reinterpret_cast<const short8*>(               \
                        reinterpret_cast<const char*>(Wlds[buf]) +            \
                        (wc * 32 + ni * 16 + lmod) * (LDSTRIDE * 2) + kb * 2);\
                _Pragma("unroll")                                             \
                for (int mi = 0; mi < 2; ++mi)                                \
                    _Pragma("unroll")                                         \
                    for (int ni = 0; ni < 2; ++ni)                            \
                        acc[mi][ni] = __builtin_amdgcn_mfma_f32_16x16x32_bf16(\
                            a[mi], bfr[ni], acc[mi][ni], 0, 0, 0);            \
            }                                                                 \
        }

    // ---- prologue: fill buffer 0 ----
    LOADT(0);
    STORET(0);

    // ---- main loop: 1 barrier per K-step, loads for t+1 in flight over
    //      MFMA of t, converts+writes go to the other buffer ----
    #pragma unroll
    for (int t = 0; t < NSTEP; ++t) {
        __syncthreads();
        if (t + 1 < NSTEP) LOADT(t + 1);
        COMPUTE(t & 1);
        if (t + 1 < NSTEP) STORET((t + 1) & 1);
    }

    // ---- epilogue: D[row = 4*(lane>>4)+r][col = lane&15] per fragment ----
    const int rowbase = bbase + wr * 32 + (ldiv << 2);
    #pragma unroll
    for (int ni = 0; ni < 2; ++ni) {
        const int o  = wc * 32 + ni * 16 + lmod;
        const float bv = bias[g * F_OUT + o];
        #pragma unroll
        for (int mi = 0; mi < 2; ++mi) {
            #pragma unroll
            for (int r = 0; r < 4; ++r) {
                const int brow = rowbase + mi * 16 + r;
                out[(size_t)brow * (G_SZ * F_OUT) + g * F_OUT + o] = acc[mi][ni][r] + bv;
            }
        }
    }
}

extern "C" void kernel_launch(void* const* d_in, const int* in_sizes, int n_in,
                              void* d_out, int out_size, void* d_ws, size_t ws_size,
                              hipStream_t stream) {
    const float* x    = (const float*)d_in[0];
    const int*   idx  = (const int*)d_in[1];
    const float* W    = (const float*)d_in[2];
    const float* bias = (const float*)d_in[3];
    float*       out  = (float*)d_out;

    sparse_linear_kernel<<<dim3(G_SZ * (B_SZ / M_TILE)), dim3(THREADS), 0, stream>>>(
        x, idx, W, bias, out);
}

// Round 3
// 26.056 us; speedup vs baseline: 1.1504x; 1.0287x over previous
//
#include <hip/hip_runtime.h>
#include <hip/hip_bf16.h>

#define B_SZ   256
#define N_IN   128
#define F_IN   64
#define G_SZ   128
#define F_OUT  64
#define S_SZ   16
#define K_TOT  1024   // S_SZ * F_IN

#define M_TILE 64
#define BK     64
#define NSTEP  16     // K_TOT / BK
#define THREADS 256   // 4 waves: wave grid 2 (M) x 2 (N)

// LDS row stride in bf16 elements: 64 + 8 pad = 72 (144 B): <=2-way bank
// aliasing on ds_read_b128 (free per m136)
#define LDSTRIDE 72

typedef __attribute__((ext_vector_type(8))) short short8;  // 8 bf16 (4 VGPRs)
typedef __attribute__((ext_vector_type(4))) float f32x4;

static __device__ __forceinline__ unsigned int packbf2(float a, float b) {
    // low 16 = a, high 16 = b (RNE); compiler emits v_cvt_pk_bf16_f32
    __hip_bfloat162 h = __float22bfloat162_rn(make_float2(a, b));
    union { __hip_bfloat162 h; unsigned int u; } c; c.h = h;
    return c.u;
}

__global__ __launch_bounds__(THREADS, 2)
void sparse_linear_kernel(const float* __restrict__ x,
                          const int*   __restrict__ idx,
                          const float* __restrict__ W,
                          const float* __restrict__ bias,
                          float*       __restrict__ out)
{
    __shared__ unsigned short Alds[2][M_TILE * LDSTRIDE];
    __shared__ unsigned short Wlds[2][F_OUT * LDSTRIDE];

    const int blk = blockIdx.x;
    // blocks {g, g+128, g+256, g+384} share W[g]; 128 % 8 == 0 -> same XCD L2
    const int g     = blk & 127;
    const int mt    = blk >> 7;          // 0..3
    const int bbase = mt * M_TILE;

    const int tid  = threadIdx.x;
    const int wave = tid >> 6;
    const int lane = tid & 63;
    const int wr   = wave >> 1;          // 0..1 (M, 32 rows each)
    const int wc   = wave & 1;           // 0..1 (N, 32 cols each)
    const int lmod = lane & 15;
    const int ldiv = lane >> 4;

    // ---- fixed per-thread staging addresses ----
    // id = tid + i*256 -> r = id>>4 (0..63), f = (id&15)*4 ; same pattern for A and W
    const float* aptr[4];
    const float* wptr[4];
    int lofs[4];                          // LDS byte offset
    #pragma unroll
    for (int i = 0; i < 4; ++i) {
        int id = tid + i * THREADS;
        int r  = id >> 4;
        int f  = (id & 15) << 2;
        aptr[i] = x + (size_t)(bbase + r) * (N_IN * F_IN) + f;
        wptr[i] = W + (size_t)g * F_OUT * K_TOT + (size_t)r * K_TOT + f;
        lofs[i] = r * (LDSTRIDE * 2) + f * 2;
    }

    // gathered row indices: wave-uniform -> SGPRs
    int rows[NSTEP];
    #pragma unroll
    for (int s = 0; s < NSTEP; ++s) rows[s] = idx[g * S_SZ + s];

    f32x4 acc[2][2] = {};                 // 2 m-frags x 2 n-frags of 16x16
    float4 ra[2][4], rw[2][4];            // 2 prefetch sets in flight

    // issue global loads for K-step t into register set s (step t covers s=t, f=0..63)
    #define LOADT(t, s)                                                       \
        {                                                                     \
            const int row = rows[t];                                          \
            _Pragma("unroll")                                                 \
            for (int i = 0; i < 4; ++i)                                       \
                ra[s][i] = *reinterpret_cast<const float4*>(aptr[i] + row * F_IN); \
            _Pragma("unroll")                                                 \
            for (int i = 0; i < 4; ++i)                                       \
                rw[s][i] = *reinterpret_cast<const float4*>(wptr[i] + (t) * BK);   \
        }

    // convert + write register set s into LDS buffer `buf`
    #define STORET(s, buf)                                                    \
        {                                                                     \
            _Pragma("unroll")                                                 \
            for (int i = 0; i < 4; ++i) {                                     \
                uint2 p;                                                      \
                p.x = packbf2(ra[s][i].x, ra[s][i].y);                        \
                p.y = packbf2(ra[s][i].z, ra[s][i].w);                        \
                *reinterpret_cast<uint2*>(                                    \
                    reinterpret_cast<char*>(Alds[buf]) + lofs[i]) = p;        \
            }                                                                 \
            _Pragma("unroll")                                                 \
            for (int i = 0; i < 4; ++i) {                                     \
                uint2 p;                                                      \
                p.x = packbf2(rw[s][i].x, rw[s][i].y);                        \
                p.y = packbf2(rw[s][i].z, rw[s][i].w);                        \
                *reinterpret_cast<uint2*>(                                    \
                    reinterpret_cast<char*>(Wlds[buf]) + lofs[i]) = p;        \
            }                                                                 \
        }

    #define COMPUTE(buf)                                                      \
        {                                                                     \
            _Pragma("unroll")                                                 \
            for (int ks = 0; ks < 2; ++ks) {                                  \
                const int kb = ks * 32 + (ldiv << 3);                         \
                short8 a[2], bfr[2];                                          \
                _Pragma("unroll")                                             \
                for (int mi = 0; mi < 2; ++mi)                                \
                    a[mi] = *reinterpret_cast<const short8*>(                 \
                        reinterpret_cast<const char*>(Alds[buf]) +            \
                        (wr * 32 + mi * 16 + lmod) * (LDSTRIDE * 2) + kb * 2);\
                _Pragma("unroll")                                             \
                for (int ni = 0; ni < 2; ++ni)                                \
                    bfr[ni] = *reinterpret_cast<const short8*>(               \
                        reinterpret_cast<const char*>(Wlds[buf]) +            \
                        (wc * 32 + ni * 16 + lmod) * (LDSTRIDE * 2) + kb * 2);\
                _Pragma("unroll")                                             \
                for (int mi = 0; mi < 2; ++mi)                                \
                    _Pragma("unroll")                                         \
                    for (int ni = 0; ni < 2; ++ni)                            \
                        acc[mi][ni] = __builtin_amdgcn_mfma_f32_16x16x32_bf16(\
                            a[mi], bfr[ni], acc[mi][ni], 0, 0, 0);            \
            }                                                                 \
        }

    // ---- prologue: two load sets in flight, buffer 0 filled ----
    LOADT(0, 0);
    LOADT(1, 1);
    STORET(0, 0);          // waits only set 0 (set 1 stays in flight: vmcnt(8))

    // ---- main loop: depth-2 pipeline, 1 barrier per K-step ----
    // step s lives in register set s&1 and LDS buffer s&1
    #pragma unroll
    for (int t = 0; t < NSTEP; ++t) {
        __syncthreads();                              // buf[t&1] ready
        if (t + 2 < NSTEP) LOADT(t + 2, t & 1);       // issue-only, 8 loads
        COMPUTE(t & 1);
        if (t + 1 < NSTEP) STORET((t + 1) & 1, (t + 1) & 1);  // regs from iter t-1
    }

    // ---- epilogue: D[row = 4*(lane>>4)+r][col = lane&15] per fragment ----
    const int rowbase = bbase + wr * 32 + (ldiv << 2);
    #pragma unroll
    for (int ni = 0; ni < 2; ++ni) {
        const int o  = wc * 32 + ni * 16 + lmod;
        const float bv = bias[g * F_OUT + o];
        #pragma unroll
        for (int mi = 0; mi < 2; ++mi) {
            #pragma unroll
            for (int r = 0; r < 4; ++r) {
                const int brow = rowbase + mi * 16 + r;
                out[(size_t)brow * (G_SZ * F_OUT) + g * F_OUT + o] = acc[mi][ni][r] + bv;
            }
        }
    }
}

extern "C" void kernel_launch(void* const* d_in, const int* in_sizes, int n_in,
                              void* d_out, int out_size, void* d_ws, size_t ws_size,
                              hipStream_t stream) {
    const float* x    = (const float*)d_in[0];
    const int*   idx  = (const int*)d_in[1];
    const float* W    = (const float*)d_in[2];
    const float* bias = (const float*)d_in[3];
    float*       out  = (float*)d_out;

    sparse_linear_kernel<<<dim3(G_SZ * (B_SZ / M_TILE)), dim3(THREADS), 0, stream>>>(
        x, idx, W, bias, out);
}